// Round 8
// baseline (633.099 us; speedup 1.0000x reference)
//
#include <hip/hip_runtime.h>
#include <hip/hip_bf16.h>
#include <math.h>

#define BB 256
#define NN 184
#define HH 128
#define FF 8
#define TH 24
#define TF 24
#define KA 160       // augmented K (128 h + x block + pad; k=139 = bias col)
#define NG2 640      // 5 gate-parts x 128 (R, Z, NH, NX, NXH)
#define RPAD 192     // padded row count (12 tiles of 16)
#define STRH 136     // Ah row stride (elems)
#define NT 1024      // 16 waves, 4/SIMD
#define NW3 552      // mask words per (b,t)
#define LOG2E 1.44269504088896f

// per-(b,fore-t) staging record, 16B-granular, layout mirrored in LDS:
//   [mask 552*8 = 4416][dinv 184*4 = 736][G 184*4 = 736][AxF 184*16 = 2944] = 8832
#define REC_F 8832
#define OFF_DINV 4416
#define OFF_G 5152
#define OFF_AXF 5888

typedef __attribute__((ext_vector_type(8))) short bf16x8;
typedef __attribute__((ext_vector_type(4))) short bf16x4;
typedef __attribute__((ext_vector_type(4))) float f32x4;
typedef __attribute__((ext_vector_type(2))) unsigned u32x2;

#if __has_builtin(__builtin_amdgcn_mfma_f32_16x16x16bf16_1k)
#define XK16 1
#else
#define XK16 0
#endif

#if __has_builtin(__builtin_amdgcn_exp2f)
#define EXP2(x) __builtin_amdgcn_exp2f(x)
#else
#define EXP2(x) exp2f(x)
#endif

__device__ __forceinline__ unsigned short f2bf(float f) {
    unsigned u = __float_as_uint(f);
    u += 0x7fffu + ((u >> 16) & 1u);
    return (unsigned short)(u >> 16);
}
__device__ __forceinline__ unsigned pkbf(float a, float b) {
    __hip_bfloat162 h = __float22bfloat162_rn(make_float2(a, b));
    return *reinterpret_cast<unsigned*>(&h);
}
__device__ __forceinline__ void gload16(const void* src, void* dst) {
    __builtin_amdgcn_global_load_lds(
        (const __attribute__((address_space(1))) unsigned int*)src,
        (__attribute__((address_space(3))) unsigned int*)dst, 16, 0, 0);
}

// ---------------------------------------------------------------------------
// Augmented bf16 weights Wa[640][160] (R, Z, NH, NX, NXH), PRESCALED:
//   R,Z rows * log2e ; NH,NX,NXH rows * 2*log2e.
// HIST (WaH) xn-FOLDING: xn_t = fcw.h_t + fcb is linear in h ->
//   R,Z h-parts get + W_xn (x) fcw (rank-1), biases get + W_xn*fcb; part 4
//   (NXH) is the n-gate's xn rank-1 h-part (hist only).
// X-block slots (k-128): 0..7 = features (hist: slot0 = p), 8 = xn (fore;
// hist: t=0 correction -fcb), 9 = g, 11 = bias (pairs with const-1).
// ---------------------------------------------------------------------------
__global__ void prep_weights(const float* __restrict__ WhhH, const float* __restrict__ WihH,
                             const float* __restrict__ WhhF, const float* __restrict__ WihF,
                             const float* __restrict__ bihH, const float* __restrict__ bhhH,
                             const float* __restrict__ bihF, const float* __restrict__ bhhF,
                             const float* __restrict__ fchw, const float* __restrict__ fchb,
                             unsigned short* __restrict__ WaH, unsigned short* __restrict__ WaF) {
    int idx = blockIdx.x * 256 + threadIdx.x;
    if (idx >= NG2 * KA) return;
    int jp = idx / KA, k = idx % KA;
    int j = jp & 127, part = jp >> 7;
    float vh = 0.f, vf = 0.f;
    if (part <= 1) {              // R, Z
        int row = part * 128 + j;
        if (k < 128) {
            vh = WhhH[row * 128 + k] + WihH[row * 2 + 0] * fchw[k];   // xn fold
            vf = WhhF[row * 128 + k];
        } else {
            int s = k - 128;
            if (s == 0)  vh = WihH[row * 2 + 1];                      // p
            if (s < 8)   vf = WihF[row * 10 + (s + 1)];
            if (s == 8)  { vh = WihH[row * 2 + 0]; vf = WihF[row * 10 + 0]; }
            if (s == 9)  vf = WihF[row * 10 + 9];
            if (s == 11) {
                vh = bihH[row] + bhhH[row] + WihH[row * 2 + 0] * fchb[0];
                vf = bihF[row] + bhhF[row];
            }
        }
    } else if (part == 2) {       // NH: h part of n-gate + bhh at bias col
        if (k < 128) { vh = WhhH[(256 + j) * 128 + k]; vf = WhhF[(256 + j) * 128 + k]; }
        else if (k == 139) { vh = bhhH[256 + j]; vf = bhhF[256 + j]; }
    } else if (part == 3) {       // NX: x part of n-gate | bih@139
        if (k >= 128) {
            int s = k - 128;
            if (s == 0)  vh = WihH[(256 + j) * 2 + 1];
            if (s < 8)   vf = WihF[(256 + j) * 10 + (s + 1)];
            if (s == 8)  { vh = WihH[(256 + j) * 2 + 0]; vf = WihF[(256 + j) * 10 + 0]; }
            if (s == 9)  vf = WihF[(256 + j) * 10 + 9];
            if (s == 11) {
                vh = bihH[256 + j] + WihH[(256 + j) * 2 + 0] * fchb[0];
                vf = bihF[256 + j];
            }
        }
    } else {                      // NXH: rank-1 W_xn(n) (x) fcw, hist only
        if (k < 128) vh = WihH[(256 + j) * 2 + 0] * fchw[k];
    }
    float sc = (part <= 1) ? LOG2E : 2.0f * LOG2E;
    WaH[idx] = f2bf(vh * sc);
    WaF[idx] = f2bf(vf * sc);
}

// ---------------------------------------------------------------------------
// Sparse edge list over adj: rec = (c1, c2, i, j) as float4.
// ---------------------------------------------------------------------------
__global__ void prep_edges(const float* __restrict__ angles, const float* __restrict__ adj,
                           float4* __restrict__ edges, int* __restrict__ cnt) {
    int idx = blockIdx.x * 256 + threadIdx.x;
    if (idx < NN * NN && adj[idx] > 0.f) {
        float a = angles[idx];
        int pos = atomicAdd(cnt, 1);
        float4 r;
        r.x = cosf(a);
        r.y = cosf(a - 1.57079632679489662f);
        r.z = __int_as_float(idx / NN);   // i (source)
        r.w = __int_as_float(idx % NN);   // j (dest)
        edges[pos] = r;
    }
}

// ---------------------------------------------------------------------------
// Persistent fused kernel. Record-building is FOLDED INTO hist steps:
// hist step t (t = 0..23) builds fore-record t in-block:
//   P1 feature->LDS + zero | bar | P2 edge loop | bar | P3 dinv/sI | bar |
//   P4 mask-write + 4-lane-group gather + G finalize + record write
//   -> GEMM -> bar   (the post-GEMM barrier separates P4 reads from the
//   next step's P1 writes; +3 barriers per hist step total).
// Records round-trip through xrec; the same block stages them back with
// global_load_lds at fore steps (ordering via the interleaved barriers'
// vmcnt drains). Fore steps unchanged from r7.
// ---------------------------------------------------------------------------
__global__ __launch_bounds__(NT, 4) void fused_dgc(
    const unsigned short* __restrict__ WaH,
    const unsigned short* __restrict__ WaF,
    const float* __restrict__ fchw, const float* __restrict__ fchb,
    const float* __restrict__ fcow, const float* __restrict__ fcob,
    const float* __restrict__ cw0, const float* __restrict__ cw1,
    const float* __restrict__ cbb,
    const float* __restrict__ feature, const float* __restrict__ pm25,
    const float4* __restrict__ edges, const int* __restrict__ ecnt,
    char* __restrict__ xrec,
    float* __restrict__ pred)
{
    __shared__ unsigned short Ah[2][RPAD * STRH];   // 104,448 B
    __shared__ unsigned short AxR[RPAD * 8];        //   3,072 B (xn, g, -, 1.0, 0..)
    __shared__ __align__(16) char stg[2][8960];     //  17,920 B
    __shared__ float xnraw[2][RPAD];                //   1,536 B (raw fc sums, dbuf)
    __shared__ float fcls_f[132];                   //     528 B (fc w fp32 + bias@128)
    __shared__ unsigned short zero16[8];            //      16 B
    __shared__ __align__(16) unsigned short phist_s[TH * NN + 16];  // 8,864 B
    // record-builder scratch (live only in hist steps)
    __shared__ float f8[NN * FF];                   //   5,888 B
    __shared__ unsigned long long mT[NN * 3];       //   4,416 B
    __shared__ int dg[NN];                          //     736 B
    __shared__ float2 dsI[NN];                      //   1,472 B (.x = dinv, .y = dinv*(f.w1))
    __shared__ float cwS[17];                       //      68 B (w1[8], w0[8], cb)

    const int tid = threadIdx.x;
    const int bb = blockIdx.x;
    const int w = tid >> 6, lane = tid & 63, q = lane >> 4, lq = lane & 15;
    const int cg = w & 7, rh = w >> 3;

    for (int i = tid; i < RPAD * STRH; i += NT) Ah[0][i] = 0;
    for (int i = tid; i < RPAD * 8; i += NT)
        AxR[i] = ((i & 7) == 3) ? (unsigned short)0x3F80 : (unsigned short)0;
    if (tid < 8) zero16[tid] = 0;
    if (tid < RPAD) { xnraw[0][tid] = 0.f; xnraw[1][tid] = 0.f; }
    if (tid < 17)
        cwS[tid] = (tid < 8) ? cw1[tid + 1] : ((tid < 16) ? cw0[tid - 7] : cbb[0]);

    // ---- pm25 -> bf16 LDS (was prep_hist) ----
    {
        const float4* psrc = (const float4*)(pm25 + (long)bb * TH * NN);
        for (int i = tid; i < (TH * NN) / 4; i += NT) {
            float4 v = psrc[i];
            u32x2 pk2;
            pk2[0] = pkbf(v.x, v.y);
            pk2[1] = pkbf(v.z, v.w);
            *(u32x2*)&phist_s[i * 4] = pk2;
        }
    }

    // ---- phase weights in registers ----
    bf16x8 wregH[4][4];   // parts: R,Z,NH (+NXH hist) : kc 0..3 (h part)
#if XK16
    bf16x4 wregX[4];      // R,Z,NH,NX : x block, K=16
#else
    bf16x8 wregX[4];      // K=32 fallback
#endif
    auto load_w = [&](const unsigned short* Wa, const float* fcw, const float* fcb, bool h4) {
        const int jcol = cg * 16 + lq;
        #pragma unroll
        for (int g = 0; g < 3; ++g)
            #pragma unroll
            for (int kc = 0; kc < 4; ++kc)
                wregH[g][kc] = *(const bf16x8*)(Wa + (long)(g * 128 + jcol) * KA + kc * 32 + q * 8);
        if (h4)
            #pragma unroll
            for (int kc = 0; kc < 4; ++kc)
                wregH[3][kc] = *(const bf16x8*)(Wa + (long)(4 * 128 + jcol) * KA + kc * 32 + q * 8);
        #pragma unroll
        for (int g = 0; g < 4; ++g)
#if XK16
            wregX[g] = *(const bf16x4*)(Wa + (long)(g * 128 + jcol) * KA + 128 + q * 4);
#else
            wregX[g] = *(const bf16x8*)(Wa + (long)(g * 128 + jcol) * KA + 128 + q * 8);
#endif
        if (tid < 132) fcls_f[tid] = (tid < 128) ? fcw[tid] : ((tid == 128) ? fcb[0] : 0.f);
    };
    load_w(WaH, fchw, fchb, true);

    const int nE = *ecnt;
    const float w00 = cw0[0], w10 = cw1[0];
    const float fcbH = fchb[0], fcbO = fcob[0];
    const f32x4 zf = {0.f, 0.f, 0.f, 0.f};

    int p = 0;
    __syncthreads();       // init visible

    for (int t = 0; t < TH + TF; ++t) {
        const bool hist = (t < TH);
        const bool dofc = (t >= TH - 1);
        const unsigned short* AxFS = (const unsigned short*)(stg[p] + OFF_AXF);

        if (hist) {
            // ====== build fore-record t (P1..P4), overlapped with hist =====
            char* rec = xrec + ((long)bb * TF + t) * REC_F;
            // P1: feature load + zero
            const float4* fsrc = (const float4*)(feature + ((long)bb * (TH + TF) + TH + t) * (NN * FF));
            for (int i = tid; i < (NN * FF) / 4; i += NT) ((float4*)f8)[i] = fsrc[i];
            for (int i = tid; i < NN * 3; i += NT) mT[i] = 0ull;
            if (tid < NN) dg[tid] = 0;
            __syncthreads();
            // P2: edge loop
            for (int e = tid; e < nE; e += NT) {
                float4 r = edges[e];
                int ii = __float_as_int(r.z), jj = __float_as_int(r.w);
                if (f8[ii * FF] * r.x + f8[ii * FF + 1] * r.y >= 0.5f) {
                    atomicAdd(&dg[ii], 1);
                    atomicOr(&mT[jj * 3 + (ii >> 6)], 1ull << (ii & 63));
                }
            }
            __syncthreads();
            // P3: dinv + scalar gather weight  sI = d * (f . w1)
            if (tid < NN) {
                float d = (dg[tid] > 0) ? rsqrtf((float)dg[tid]) : 0.f;
                float s = 0.f;
                #pragma unroll
                for (int c = 0; c < 8; ++c) s = fmaf(f8[tid * FF + c], cwS[c], s);
                dsI[tid] = make_float2(d, d * s);
            }
            __syncthreads();
            // P4: mask write + 4-lane-group gather + G finalize + record out
            {
                const int jg = tid >> 2, wd = tid & 3;
                if (jg < NN) {
                    float acc = 0.f;
                    if (wd < 3) {
                        unsigned long long m = mT[jg * 3 + wd];
                        ((unsigned long long*)rec)[jg * 3 + wd] = m;
                        while (m) {
                            int bp = __ffsll(m) - 1; m &= m - 1;
                            acc += dsI[wd * 64 + bp].y;
                        }
                    }
                    acc += __shfl_xor(acc, 1);
                    acc += __shfl_xor(acc, 2);
                    if (wd == 0) {
                        float dj = dsI[jg].x;
                        float hzj = (dj > 0.f) ? 0.f : -1.f;
                        float S0 = 0.f, S1 = 0.f;
                        #pragma unroll
                        for (int c = 0; c < 8; ++c) {
                            float xv = f8[jg * FF + c];
                            S1 = fmaf(xv, cwS[c], S1);
                            S0 = fmaf(xv, cwS[8 + c], S0);
                        }
                        float G = cwS[16] + S0 + hzj * S1 - dj * acc;
                        ((float*)(rec + OFF_DINV))[jg] = dj;
                        ((float*)(rec + OFF_G))[jg] = G;
                        uint4 ax4;
                        ax4.x = pkbf(f8[jg * FF + 0], f8[jg * FF + 1]);
                        ax4.y = pkbf(f8[jg * FF + 2], f8[jg * FF + 3]);
                        ax4.z = pkbf(f8[jg * FF + 4], f8[jg * FF + 5]);
                        ax4.w = pkbf(f8[jg * FF + 6], f8[jg * FF + 7]);
                        *(uint4*)(rec + OFF_AXF + jg * 16) = ax4;
                    }
                }
            }
            // no barrier: GEMM deps (Ah[p], phist_s) already satisfied; the
            // post-GEMM barrier separates P4 reads from next step's P1 writes.
        } else {
            // ====== cheb phase (fore): gather + finalize + pred + zero-buf =
            const unsigned long long* maskS = (const unsigned long long*)stg[p];
            const float* dinS = (const float*)(stg[p] + OFF_DINV);
            const float* GS = (const float*)(stg[p] + OFF_G);
            const float* xr = xnraw[(t - 1) & 1];
            const float fcbP = (t == TH) ? fcbH : fcbO;
            const int jg = tid >> 2, wd = tid & 3;
            if (jg < NN) {
                float acc = 0.f, accd = 0.f;
                if (wd < 3) {
                    unsigned long long m = maskS[jg * 3 + wd];
                    while (m) {
                        int bp = __ffsll(m) - 1; m &= m - 1;
                        int i = wd * 64 + bp;
                        float d = dinS[i];
                        acc = fmaf(d, xr[i], acc);
                        accd += d;
                    }
                }
                acc  += __shfl_xor(acc, 1);  acc  += __shfl_xor(acc, 2);
                accd += __shfl_xor(accd, 1); accd += __shfl_xor(accd, 2);
                if (wd == 0) {
                    float dj = dinS[jg];
                    float xnj = xr[jg] + fcbP;
                    float hzj = (dj > 0.f) ? 0.f : -1.f;
                    float sum = fmaf(fcbP, accd, acc);        // sum di*xn
                    float y0 = -dj * sum + hzj * xnj;
                    float pre = GS[jg] + xnj * w00 + y0 * w10;
                    float g = __builtin_amdgcn_rcpf(1.0f + EXP2(-LOG2E * pre));
                    AxR[jg * 8 + 1] = f2bf(g);
                    AxR[jg * 8 + 0] = f2bf(xnj);
                    if (t > TH) pred[((long)bb * TF + (t - 1 - TH)) * NN + jg] = xnj;
                }
            } else {
                int i = tid - 736;                            // 288 idle lanes
                if (i < RPAD) xnraw[t & 1][i] = 0.f;
            }
            __syncthreads();
        }

        // ====== issue t+1 fore-record staging (lands by post-GEMM bar) =====
        const int t2 = t + 1;
        if (t2 >= TH && t2 < TH + TF && tid < NW3)
            gload16(xrec + ((long)bb * TF + (t2 - TH)) * REC_F + tid * 16,
                    (char*)stg[p ^ 1] + (tid & ~63) * 16);

        // ========== GRU GEMM + epilogue (+ fc atomics if dofc) =============
        f32x4 fw = *(const f32x4*)&fcls_f[cg * 16 + q * 4];
        const unsigned short corr0 = (t == 0) ? f2bf(-fcbH) : (unsigned short)0;
        #pragma unroll
        for (int rl = 0; rl < 6; ++rl) {
            const int row = rh * 96 + rl * 16 + lq;
            const int ro = row * STRH;
            f32x4 a0, a1, a2, a3;
            {   // kc = 0: zero-C chains (no acc zero-init movs)
                bf16x8 bh = *(const bf16x8*)(&Ah[p][ro + q * 8]);
                a0 = __builtin_amdgcn_mfma_f32_16x16x32_bf16(wregH[0][0], bh, zf, 0, 0, 0);
                a1 = __builtin_amdgcn_mfma_f32_16x16x32_bf16(wregH[1][0], bh, zf, 0, 0, 0);
                a2 = __builtin_amdgcn_mfma_f32_16x16x32_bf16(wregH[2][0], bh, zf, 0, 0, 0);
                a3 = hist ? __builtin_amdgcn_mfma_f32_16x16x32_bf16(wregH[3][0], bh, zf, 0, 0, 0)
                          : zf;
            }
            #pragma unroll
            for (int kc = 1; kc < 4; ++kc) {
                bf16x8 bh = *(const bf16x8*)(&Ah[p][ro + kc * 32 + q * 8]);
                a0 = __builtin_amdgcn_mfma_f32_16x16x32_bf16(wregH[0][kc], bh, a0, 0, 0, 0);
                a1 = __builtin_amdgcn_mfma_f32_16x16x32_bf16(wregH[1][kc], bh, a1, 0, 0, 0);
                a2 = __builtin_amdgcn_mfma_f32_16x16x32_bf16(wregH[2][kc], bh, a2, 0, 0, 0);
                if (hist)
                    a3 = __builtin_amdgcn_mfma_f32_16x16x32_bf16(wregH[3][kc], bh, a3, 0, 0, 0);
            }
#if XK16
            bf16x4 bx;
            if (hist) {
                unsigned short pb = phist_s[t * NN + row];
                bf16x4 z = {0,0,0,0};
                bx = z;
                if (q == 0) bx[0] = (short)pb;
                if (q == 2) { bx[0] = (short)corr0; bx[3] = (short)0x3F80; }
            } else {
                const unsigned short* bxp = (q < 2) ? (AxFS + row * 8 + q * 4)
                                          : (q == 2) ? (AxR + row * 8) : zero16;
                bx = *(const bf16x4*)bxp;
            }
            a0 = __builtin_amdgcn_mfma_f32_16x16x16bf16_1k(wregX[0], bx, a0, 0, 0, 0);
            a1 = __builtin_amdgcn_mfma_f32_16x16x16bf16_1k(wregX[1], bx, a1, 0, 0, 0);
            a2 = __builtin_amdgcn_mfma_f32_16x16x16bf16_1k(wregX[2], bx, a2, 0, 0, 0);
            a3 = __builtin_amdgcn_mfma_f32_16x16x16bf16_1k(wregX[3], bx, a3, 0, 0, 0);
#else
            bf16x8 bx;
            if (hist) {
                unsigned short pb = phist_s[t * NN + row];
                bf16x8 z = {0,0,0,0,0,0,0,0};
                bx = z;
                if (q == 0) bx[0] = (short)pb;
                if (q == 1) { bx[0] = (short)corr0; bx[3] = (short)0x3F80; }
            } else {
                const unsigned short* bxp = (q == 0) ? (AxFS + row * 8)
                                          : (q == 1) ? (AxR + row * 8) : zero16;
                bx = *(const bf16x8*)bxp;
            }
            a0 = __builtin_amdgcn_mfma_f32_16x16x32_bf16(wregX[0], bx, a0, 0, 0, 0);
            a1 = __builtin_amdgcn_mfma_f32_16x16x32_bf16(wregX[1], bx, a1, 0, 0, 0);
            a2 = __builtin_amdgcn_mfma_f32_16x16x32_bf16(wregX[2], bx, a2, 0, 0, 0);
            a3 = __builtin_amdgcn_mfma_f32_16x16x32_bf16(wregX[3], bx, a3, 0, 0, 0);
#endif

            // h_old readback (same bf16 this wave wrote last step)
            u32x2 hold = *(const u32x2*)&Ah[p][ro + cg * 16 + q * 4];

            float hn[4];
            #pragma unroll
            for (int rg = 0; rg < 4; ++rg) {
                unsigned hu = hold[rg >> 1];
                float ho = ((rg & 1) == 0) ? __uint_as_float(hu << 16)
                                           : __uint_as_float(hu & 0xffff0000u);
                // a0,a1 prescaled by log2e; a2,a3 by 2*log2e (biases folded)
                float rr = __builtin_amdgcn_rcpf(1.0f + EXP2(-a0[rg]));
                float zz = __builtin_amdgcn_rcpf(1.0f + EXP2(-a1[rg]));
                float wv = fmaf(rr, a2[rg], a3[rg]);
                // tanh(v) = 2*sigmoid(2v) - 1 ; wv = 2*log2e*v
                float s2 = __builtin_amdgcn_rcpf(1.0f + EXP2(-wv));
                float tv = fmaf(2.0f, s2, -1.0f);
                hn[rg] = fmaf(zz, ho - tv, tv);
            }
            u32x2 pk;
            pk[0] = pkbf(hn[0], hn[1]);
            pk[1] = pkbf(hn[2], hn[3]);
            *(u32x2*)&Ah[p ^ 1][ro + cg * 16 + q * 4] = pk;
            if (dofc) {
                // fc partial (fp32, raw): reduce over q, publish via ds atomic
                float pf = hn[0] * fw.x + hn[1] * fw.y + hn[2] * fw.z + hn[3] * fw.w;
                pf += __shfl_xor(pf, 16);
                pf += __shfl_xor(pf, 32);
                if (q == 0) atomicAdd(&xnraw[t & 1][row], pf);
            }
        }
        __syncthreads();

        if (t == TH - 1)
            load_w(WaF, fcow, fcob, false);
        p ^= 1;
    }

    // ---- tail: last prediction (xn of final fore step) ----
    if (tid < NN)
        pred[((long)bb * TF + (TF - 1)) * NN + tid] =
            xnraw[(TH + TF - 1) & 1][tid] + fcbO;
}

extern "C" void kernel_launch(void* const* d_in, const int* in_sizes, int n_in,
                              void* d_out, int out_size, void* d_ws, size_t ws_size,
                              hipStream_t stream) {
    const float* feature = (const float*)d_in[0];
    const float* pm25    = (const float*)d_in[1];
    const float* adj     = (const float*)d_in[2];
    const float* angles  = (const float*)d_in[3];
    const float* W_ih_h  = (const float*)d_in[4];
    const float* W_hh_h  = (const float*)d_in[5];
    const float* b_ih_h  = (const float*)d_in[6];
    const float* b_hh_h  = (const float*)d_in[7];
    const float* fch_w   = (const float*)d_in[8];
    const float* fch_b   = (const float*)d_in[9];
    const float* cw0     = (const float*)d_in[10];
    const float* cw1     = (const float*)d_in[11];
    const float* cbb     = (const float*)d_in[12];
    const float* W_ih    = (const float*)d_in[13];
    const float* W_hh    = (const float*)d_in[14];
    const float* b_ih    = (const float*)d_in[15];
    const float* b_hh    = (const float*)d_in[16];
    const float* fco_w   = (const float*)d_in[17];
    const float* fco_b   = (const float*)d_in[18];
    float* pred = (float*)d_out;

    char* ws = (char*)d_ws;
    size_t off = 0;
    unsigned short* WaH   = (unsigned short*)(ws + off); off += (size_t)NG2 * KA * 2;  //   204,800
    unsigned short* WaF   = (unsigned short*)(ws + off); off += (size_t)NG2 * KA * 2;
    float4*         edges = (float4*)(ws + off);         off += (size_t)NN * NN * 16;  //   541,696
    int*            cnt   = (int*)(ws + off);            off += 16;
    char*           xrec  = (char*)(ws + off);
    off += (size_t)BB * TF * REC_F;                                                    // 54,263,808

    hipMemsetAsync(cnt, 0, 16, stream);
    prep_weights<<<(NG2 * KA + 255) / 256, 256, 0, stream>>>(
        W_hh_h, W_ih_h, W_hh, W_ih, b_ih_h, b_hh_h, b_ih, b_hh, fch_w, fch_b,
        WaH, WaF);
    prep_edges<<<(NN * NN + 255) / 256, 256, 0, stream>>>(angles, adj, edges, cnt);

    fused_dgc<<<BB, NT, 0, stream>>>(
        WaH, WaF, fch_w, fch_b, fco_w, fco_b, cw0, cw1, cbb,
        feature, pm25, edges, cnt, xrec, pred);
}

// Round 9
// 578.880 us; speedup vs baseline: 1.0937x; 1.0937x over previous
//
#include <hip/hip_runtime.h>
#include <hip/hip_bf16.h>
#include <math.h>

#define BB 256
#define NN 184
#define HH 128
#define FF 8
#define TH 24
#define TF 24
#define KA 160       // augmented K (128 h + x block + pad; k=139 = bias col)
#define NG2 640      // 5 gate-parts x 128 (R, Z, NH, NX, NXH)
#define RPAD 192     // padded row count (12 tiles of 16)
#define STRH 136     // Ah row stride (elems)
#define NT 1024      // 16 waves, 4/SIMD
#define NW3 552      // mask words per (b,t)
#define LOG2E 1.44269504088896f

// per-(b,fore-t) staging record, 16B-granular, layout mirrored in LDS:
//   [mask 552*8 = 4416][dinv 184*4 = 736][G 184*4 = 736][AxF 184*16 = 2944] = 8832
#define REC_F 8832
#define OFF_DINV 4416
#define OFF_G 5152
#define OFF_AXF 5888

typedef __attribute__((ext_vector_type(8))) short bf16x8;
typedef __attribute__((ext_vector_type(4))) short bf16x4;
typedef __attribute__((ext_vector_type(4))) float f32x4;
typedef __attribute__((ext_vector_type(2))) unsigned u32x2;

#if __has_builtin(__builtin_amdgcn_mfma_f32_16x16x16bf16_1k)
#define XK16 1
#else
#define XK16 0
#endif

#if __has_builtin(__builtin_amdgcn_exp2f)
#define EXP2(x) __builtin_amdgcn_exp2f(x)
#else
#define EXP2(x) exp2f(x)
#endif

__device__ __forceinline__ unsigned short f2bf(float f) {
    unsigned u = __float_as_uint(f);
    u += 0x7fffu + ((u >> 16) & 1u);
    return (unsigned short)(u >> 16);
}
__device__ __forceinline__ unsigned pkbf(float a, float b) {
    __hip_bfloat162 h = __float22bfloat162_rn(make_float2(a, b));
    return *reinterpret_cast<unsigned*>(&h);
}
__device__ __forceinline__ void gload16(const void* src, void* dst) {
    __builtin_amdgcn_global_load_lds(
        (const __attribute__((address_space(1))) unsigned int*)src,
        (__attribute__((address_space(3))) unsigned int*)dst, 16, 0, 0);
}

// ---------------------------------------------------------------------------
// Augmented bf16 weights Wa[640][160] (R, Z, NH, NX, NXH), PRESCALED:
//   R,Z rows * log2e ; NH,NX,NXH rows * 2*log2e.
// HIST (WaH) xn-FOLDING: xn_t = fcw.h_t + fcb is linear in h ->
//   R,Z h-parts get + W_xn (x) fcw (rank-1), biases get + W_xn*fcb; part 4
//   (NXH) is the n-gate's xn rank-1 h-part (hist only).
// X-block slots (k-128): 0..7 = features (hist: slot0 = p), 8 = xn (fore;
// hist: t=0 correction -fcb), 9 = g, 11 = bias (pairs with const-1).
// ---------------------------------------------------------------------------
__global__ void prep_weights(const float* __restrict__ WhhH, const float* __restrict__ WihH,
                             const float* __restrict__ WhhF, const float* __restrict__ WihF,
                             const float* __restrict__ bihH, const float* __restrict__ bhhH,
                             const float* __restrict__ bihF, const float* __restrict__ bhhF,
                             const float* __restrict__ fchw, const float* __restrict__ fchb,
                             unsigned short* __restrict__ WaH, unsigned short* __restrict__ WaF) {
    int idx = blockIdx.x * 256 + threadIdx.x;
    if (idx >= NG2 * KA) return;
    int jp = idx / KA, k = idx % KA;
    int j = jp & 127, part = jp >> 7;
    float vh = 0.f, vf = 0.f;
    if (part <= 1) {              // R, Z
        int row = part * 128 + j;
        if (k < 128) {
            vh = WhhH[row * 128 + k] + WihH[row * 2 + 0] * fchw[k];   // xn fold
            vf = WhhF[row * 128 + k];
        } else {
            int s = k - 128;
            if (s == 0)  vh = WihH[row * 2 + 1];                      // p
            if (s < 8)   vf = WihF[row * 10 + (s + 1)];
            if (s == 8)  { vh = WihH[row * 2 + 0]; vf = WihF[row * 10 + 0]; }
            if (s == 9)  vf = WihF[row * 10 + 9];
            if (s == 11) {
                vh = bihH[row] + bhhH[row] + WihH[row * 2 + 0] * fchb[0];
                vf = bihF[row] + bhhF[row];
            }
        }
    } else if (part == 2) {       // NH: h part of n-gate + bhh at bias col
        if (k < 128) { vh = WhhH[(256 + j) * 128 + k]; vf = WhhF[(256 + j) * 128 + k]; }
        else if (k == 139) { vh = bhhH[256 + j]; vf = bhhF[256 + j]; }
    } else if (part == 3) {       // NX: x part of n-gate | bih@139
        if (k >= 128) {
            int s = k - 128;
            if (s == 0)  vh = WihH[(256 + j) * 2 + 1];
            if (s < 8)   vf = WihF[(256 + j) * 10 + (s + 1)];
            if (s == 8)  { vh = WihH[(256 + j) * 2 + 0]; vf = WihF[(256 + j) * 10 + 0]; }
            if (s == 9)  vf = WihF[(256 + j) * 10 + 9];
            if (s == 11) {
                vh = bihH[256 + j] + WihH[(256 + j) * 2 + 0] * fchb[0];
                vf = bihF[256 + j];
            }
        }
    } else {                      // NXH: rank-1 W_xn(n) (x) fcw, hist only
        if (k < 128) vh = WihH[(256 + j) * 2 + 0] * fchw[k];
    }
    float sc = (part <= 1) ? LOG2E : 2.0f * LOG2E;
    WaH[idx] = f2bf(vh * sc);
    WaF[idx] = f2bf(vf * sc);
}

// ---------------------------------------------------------------------------
// Sparse edge list over adj: rec = (c1, c2, i, j) as float4.
// ---------------------------------------------------------------------------
__global__ void prep_edges(const float* __restrict__ angles, const float* __restrict__ adj,
                           float4* __restrict__ edges, int* __restrict__ cnt) {
    int idx = blockIdx.x * 256 + threadIdx.x;
    if (idx < NN * NN && adj[idx] > 0.f) {
        float a = angles[idx];
        int pos = atomicAdd(cnt, 1);
        float4 r;
        r.x = cosf(a);
        r.y = cosf(a - 1.57079632679489662f);
        r.z = __int_as_float(idx / NN);   // i (source)
        r.w = __int_as_float(idx % NN);   // j (dest)
        edges[pos] = r;
    }
}

// ---------------------------------------------------------------------------
// Flat bf16 cast of pm25 (same memory order) -> phist.
// ---------------------------------------------------------------------------
__global__ void prep_hist(const float* __restrict__ pm25, unsigned short* __restrict__ phist) {
    int idx = blockIdx.x * 256 + threadIdx.x;
    if (idx < BB * TH * NN) phist[idx] = f2bf(pm25[idx]);
}

// ---------------------------------------------------------------------------
// Fore-record builder: one block per (batch, fore step), 1024 THREADS
// (16 waves -- 4x the workers on every serial phase vs the 256-thread
// version; edge loop 13.2 -> 3.3 iters; 3 barriers instead of 4; gather
// via 4-lane shfl groups, no red[] round-trip).
//   G_j = cb + S0_j + hz_j*S1_j - d_j * sum_{i in M(j)} s_i,
//   s_i = d_i * (f_i . w1)   (exact reassociation, bit-identical records)
// ---------------------------------------------------------------------------
__global__ __launch_bounds__(1024) void prep_graph(
    const float* __restrict__ feature,
    const float4* __restrict__ edges, const int* __restrict__ ecnt,
    const float* __restrict__ cw0, const float* __restrict__ cw1,
    const float* __restrict__ cbb, char* __restrict__ xrec)
{
    const int bt = blockIdx.x;
    const int b = bt / TF, tf = bt % TF;
    const int tt = TH + tf;
    const int tid = threadIdx.x;

    char* rec = xrec + ((long)b * TF + tf) * REC_F;

    __shared__ float f8[NN * FF];                   //  5,888 B
    __shared__ unsigned long long mT[NN * 3];       //  4,416 B
    __shared__ int dg[NN];                          //    736 B
    __shared__ float2 dsI[NN];                      //  1,472 B (.x = dinv, .y = dinv*(f.w1))

    // P1: feature load + zero
    const float4* fb4 = (const float4*)(feature + ((long)b * (TH + TF) + tt) * (NN * FF));
    for (int i = tid; i < (NN * FF) / 4; i += 1024) ((float4*)f8)[i] = fb4[i];
    for (int i = tid; i < NN * 3; i += 1024) mT[i] = 0ull;
    if (tid < NN) dg[tid] = 0;
    __syncthreads();
    // P2: edge loop (3.3 iters at 1024 threads)
    const int nE = *ecnt;
    for (int e = tid; e < nE; e += 1024) {
        float4 r = edges[e];
        int ii = __float_as_int(r.z), jj = __float_as_int(r.w);
        if (f8[ii * FF] * r.x + f8[ii * FF + 1] * r.y >= 0.5f) {
            atomicAdd(&dg[ii], 1);
            atomicOr(&mT[jj * 3 + (ii >> 6)], 1ull << (ii & 63));
        }
    }
    __syncthreads();
    // P3: dinv + scalar gather weight  sI = d * (f . w1)
    if (tid < NN) {
        float d = (dg[tid] > 0) ? rsqrtf((float)dg[tid]) : 0.f;
        float s = 0.f;
        #pragma unroll
        for (int c = 0; c < 8; ++c) s = fmaf(f8[tid * FF + c], cw1[c + 1], s);
        dsI[tid] = make_float2(d, d * s);
    }
    __syncthreads();
    // P4: mask write + 4-lane-group gather + G finalize + record out
    const int jg = tid >> 2, wd = tid & 3;
    if (jg < NN) {
        float acc = 0.f;
        if (wd < 3) {
            unsigned long long m = mT[jg * 3 + wd];
            ((unsigned long long*)rec)[jg * 3 + wd] = m;
            while (m) {
                int bp = __ffsll(m) - 1; m &= m - 1;
                acc += dsI[wd * 64 + bp].y;
            }
        }
        acc += __shfl_xor(acc, 1);
        acc += __shfl_xor(acc, 2);
        if (wd == 0) {
            float dj = dsI[jg].x;
            float hzj = (dj > 0.f) ? 0.f : -1.f;
            float S0 = 0.f, S1 = 0.f;
            #pragma unroll
            for (int c = 0; c < 8; ++c) {
                float xv = f8[jg * FF + c];
                S0 = fmaf(xv, cw0[c + 1], S0);
                S1 = fmaf(xv, cw1[c + 1], S1);
            }
            float G = cbb[0] + S0 + hzj * S1 - dj * acc;
            ((float*)(rec + OFF_DINV))[jg] = dj;
            ((float*)(rec + OFF_G))[jg] = G;
            uint4 ax4;
            ax4.x = pkbf(f8[jg * FF + 0], f8[jg * FF + 1]);
            ax4.y = pkbf(f8[jg * FF + 2], f8[jg * FF + 3]);
            ax4.z = pkbf(f8[jg * FF + 4], f8[jg * FF + 5]);
            ax4.w = pkbf(f8[jg * FF + 6], f8[jg * FF + 7]);
            *(uint4*)(rec + OFF_AXF + jg * 16) = ax4;
        }
    }
}

// ---------------------------------------------------------------------------
// Persistent fused kernel (r7 verbatim), 2 barriers per fore step (1 per
// hist step):
//   fore t: [cheb(t): gather on xnraw(t-1) + finalize g/xn/pred(t-1) + zero
//            other xnraw buf | bar]
//           [stage(t+1) + GEMM + epilogue w/ fc -> atomicAdd xnraw(t&1) | bar]
//   hist t: [GEMM(+fc at TH-1) | bar]
// ---------------------------------------------------------------------------
__global__ __launch_bounds__(NT, 4) void fused_dgc(
    const unsigned short* __restrict__ WaH,
    const unsigned short* __restrict__ WaF,
    const float* __restrict__ fchw, const float* __restrict__ fchb,
    const float* __restrict__ fcow, const float* __restrict__ fcob,
    const float* __restrict__ cw0, const float* __restrict__ cw1,
    const char* __restrict__ xrec, const unsigned short* __restrict__ phist,
    float* __restrict__ pred)
{
    __shared__ unsigned short Ah[2][RPAD * STRH];   // 104,448 B
    __shared__ unsigned short AxR[RPAD * 8];        //   3,072 B (xn, g, -, 1.0, 0..)
    __shared__ __align__(16) char stg[2][8960];     //  17,920 B
    __shared__ float xnraw[2][RPAD];                //   1,536 B (raw fc sums, dbuf)
    __shared__ float fcls_f[132];                   //     528 B (fc w fp32 + bias@128)
    __shared__ unsigned short zero16[8];            //      16 B
    __shared__ __align__(16) unsigned short phist_s[TH * NN + 16];  // 8,864 B

    const int tid = threadIdx.x;
    const int bb = blockIdx.x;
    const int w = tid >> 6, lane = tid & 63, q = lane >> 4, lq = lane & 15;
    const int cg = w & 7, rh = w >> 3;

    for (int i = tid; i < RPAD * STRH; i += NT) Ah[0][i] = 0;
    for (int i = tid; i < RPAD * 8; i += NT)
        AxR[i] = ((i & 7) == 3) ? (unsigned short)0x3F80 : (unsigned short)0;
    if (tid < 8) zero16[tid] = 0;
    if (tid < RPAD) { xnraw[0][tid] = 0.f; xnraw[1][tid] = 0.f; }

    // ---- phase weights in registers ----
    bf16x8 wregH[4][4];   // parts: R,Z,NH (+NXH hist) : kc 0..3 (h part)
#if XK16
    bf16x4 wregX[4];      // R,Z,NH,NX : x block, K=16
#else
    bf16x8 wregX[4];      // K=32 fallback
#endif
    auto load_w = [&](const unsigned short* Wa, const float* fcw, const float* fcb, bool h4) {
        const int jcol = cg * 16 + lq;
        #pragma unroll
        for (int g = 0; g < 3; ++g)
            #pragma unroll
            for (int kc = 0; kc < 4; ++kc)
                wregH[g][kc] = *(const bf16x8*)(Wa + (long)(g * 128 + jcol) * KA + kc * 32 + q * 8);
        if (h4)
            #pragma unroll
            for (int kc = 0; kc < 4; ++kc)
                wregH[3][kc] = *(const bf16x8*)(Wa + (long)(4 * 128 + jcol) * KA + kc * 32 + q * 8);
        #pragma unroll
        for (int g = 0; g < 4; ++g)
#if XK16
            wregX[g] = *(const bf16x4*)(Wa + (long)(g * 128 + jcol) * KA + 128 + q * 4);
#else
            wregX[g] = *(const bf16x8*)(Wa + (long)(g * 128 + jcol) * KA + 128 + q * 8);
#endif
        if (tid < 132) fcls_f[tid] = (tid < 128) ? fcw[tid] : ((tid == 128) ? fcb[0] : 0.f);
    };
    load_w(WaH, fchw, fchb, true);

    // ---- stage the full pm25 block (8832 B, once) ----
    if (tid < NW3)
        gload16((const char*)phist + (long)bb * (TH * NN * 2) + tid * 16,
                (char*)phist_s + (tid & ~63) * 16);

    const float w00 = cw0[0], w10 = cw1[0];
    const float fcbH = fchb[0], fcbO = fcob[0];
    const f32x4 zf = {0.f, 0.f, 0.f, 0.f};

    int p = 0;
    __syncthreads();       // init + phist visible

    for (int t = 0; t < TH + TF; ++t) {
        const bool hist = (t < TH);
        const bool dofc = (t >= TH - 1);
        const unsigned short* AxFS = (const unsigned short*)(stg[p] + OFF_AXF);

        // ====== cheb phase (fore): gather + finalize + pred + zero-buf =====
        if (!hist) {
            const unsigned long long* maskS = (const unsigned long long*)stg[p];
            const float* dinS = (const float*)(stg[p] + OFF_DINV);
            const float* GS = (const float*)(stg[p] + OFF_G);
            const float* xr = xnraw[(t - 1) & 1];
            const float fcbP = (t == TH) ? fcbH : fcbO;
            const int jg = tid >> 2, wd = tid & 3;
            if (jg < NN) {
                float acc = 0.f, accd = 0.f;
                if (wd < 3) {
                    unsigned long long m = maskS[jg * 3 + wd];
                    while (m) {
                        int bp = __ffsll(m) - 1; m &= m - 1;
                        int i = wd * 64 + bp;
                        float d = dinS[i];
                        acc = fmaf(d, xr[i], acc);
                        accd += d;
                    }
                }
                acc  += __shfl_xor(acc, 1);  acc  += __shfl_xor(acc, 2);
                accd += __shfl_xor(accd, 1); accd += __shfl_xor(accd, 2);
                if (wd == 0) {
                    float dj = dinS[jg];
                    float xnj = xr[jg] + fcbP;
                    float hzj = (dj > 0.f) ? 0.f : -1.f;
                    float sum = fmaf(fcbP, accd, acc);        // sum di*xn
                    float y0 = -dj * sum + hzj * xnj;
                    float pre = GS[jg] + xnj * w00 + y0 * w10;
                    float g = __builtin_amdgcn_rcpf(1.0f + EXP2(-LOG2E * pre));
                    AxR[jg * 8 + 1] = f2bf(g);
                    AxR[jg * 8 + 0] = f2bf(xnj);
                    if (t > TH) pred[((long)bb * TF + (t - 1 - TH)) * NN + jg] = xnj;
                }
            } else {
                int i = tid - 736;                            // 288 idle lanes
                if (i < RPAD) xnraw[t & 1][i] = 0.f;
            }
            __syncthreads();
        }

        // ====== issue t+1 fore-record staging (lands by post-GEMM bar) =====
        const int t2 = t + 1;
        if (t2 >= TH && t2 < TH + TF && tid < NW3)
            gload16(xrec + ((long)bb * TF + (t2 - TH)) * REC_F + tid * 16,
                    (char*)stg[p ^ 1] + (tid & ~63) * 16);

        // ========== GRU GEMM + epilogue (+ fc atomics if dofc) =============
        f32x4 fw = *(const f32x4*)&fcls_f[cg * 16 + q * 4];
        const unsigned short corr0 = (t == 0) ? f2bf(-fcbH) : (unsigned short)0;
        #pragma unroll
        for (int rl = 0; rl < 6; ++rl) {
            const int row = rh * 96 + rl * 16 + lq;
            const int ro = row * STRH;
            f32x4 a0, a1, a2, a3;
            {   // kc = 0: zero-C chains (no acc zero-init movs)
                bf16x8 bh = *(const bf16x8*)(&Ah[p][ro + q * 8]);
                a0 = __builtin_amdgcn_mfma_f32_16x16x32_bf16(wregH[0][0], bh, zf, 0, 0, 0);
                a1 = __builtin_amdgcn_mfma_f32_16x16x32_bf16(wregH[1][0], bh, zf, 0, 0, 0);
                a2 = __builtin_amdgcn_mfma_f32_16x16x32_bf16(wregH[2][0], bh, zf, 0, 0, 0);
                a3 = hist ? __builtin_amdgcn_mfma_f32_16x16x32_bf16(wregH[3][0], bh, zf, 0, 0, 0)
                          : zf;
            }
            #pragma unroll
            for (int kc = 1; kc < 4; ++kc) {
                bf16x8 bh = *(const bf16x8*)(&Ah[p][ro + kc * 32 + q * 8]);
                a0 = __builtin_amdgcn_mfma_f32_16x16x32_bf16(wregH[0][kc], bh, a0, 0, 0, 0);
                a1 = __builtin_amdgcn_mfma_f32_16x16x32_bf16(wregH[1][kc], bh, a1, 0, 0, 0);
                a2 = __builtin_amdgcn_mfma_f32_16x16x32_bf16(wregH[2][kc], bh, a2, 0, 0, 0);
                if (hist)
                    a3 = __builtin_amdgcn_mfma_f32_16x16x32_bf16(wregH[3][kc], bh, a3, 0, 0, 0);
            }
#if XK16
            bf16x4 bx;
            if (hist) {
                unsigned short pb = phist_s[t * NN + row];
                bf16x4 z = {0,0,0,0};
                bx = z;
                if (q == 0) bx[0] = (short)pb;
                if (q == 2) { bx[0] = (short)corr0; bx[3] = (short)0x3F80; }
            } else {
                const unsigned short* bxp = (q < 2) ? (AxFS + row * 8 + q * 4)
                                          : (q == 2) ? (AxR + row * 8) : zero16;
                bx = *(const bf16x4*)bxp;
            }
            a0 = __builtin_amdgcn_mfma_f32_16x16x16bf16_1k(wregX[0], bx, a0, 0, 0, 0);
            a1 = __builtin_amdgcn_mfma_f32_16x16x16bf16_1k(wregX[1], bx, a1, 0, 0, 0);
            a2 = __builtin_amdgcn_mfma_f32_16x16x16bf16_1k(wregX[2], bx, a2, 0, 0, 0);
            a3 = __builtin_amdgcn_mfma_f32_16x16x16bf16_1k(wregX[3], bx, a3, 0, 0, 0);
#else
            bf16x8 bx;
            if (hist) {
                unsigned short pb = phist_s[t * NN + row];
                bf16x8 z = {0,0,0,0,0,0,0,0};
                bx = z;
                if (q == 0) bx[0] = (short)pb;
                if (q == 1) { bx[0] = (short)corr0; bx[3] = (short)0x3F80; }
            } else {
                const unsigned short* bxp = (q == 0) ? (AxFS + row * 8)
                                          : (q == 1) ? (AxR + row * 8) : zero16;
                bx = *(const bf16x8*)bxp;
            }
            a0 = __builtin_amdgcn_mfma_f32_16x16x32_bf16(wregX[0], bx, a0, 0, 0, 0);
            a1 = __builtin_amdgcn_mfma_f32_16x16x32_bf16(wregX[1], bx, a1, 0, 0, 0);
            a2 = __builtin_amdgcn_mfma_f32_16x16x32_bf16(wregX[2], bx, a2, 0, 0, 0);
            a3 = __builtin_amdgcn_mfma_f32_16x16x32_bf16(wregX[3], bx, a3, 0, 0, 0);
#endif

            // h_old readback (same bf16 this wave wrote last step)
            u32x2 hold = *(const u32x2*)&Ah[p][ro + cg * 16 + q * 4];

            float hn[4];
            #pragma unroll
            for (int rg = 0; rg < 4; ++rg) {
                unsigned hu = hold[rg >> 1];
                float ho = ((rg & 1) == 0) ? __uint_as_float(hu << 16)
                                           : __uint_as_float(hu & 0xffff0000u);
                // a0,a1 prescaled by log2e; a2,a3 by 2*log2e (biases folded)
                float rr = __builtin_amdgcn_rcpf(1.0f + EXP2(-a0[rg]));
                float zz = __builtin_amdgcn_rcpf(1.0f + EXP2(-a1[rg]));
                float wv = fmaf(rr, a2[rg], a3[rg]);
                // tanh(v) = 2*sigmoid(2v) - 1 ; wv = 2*log2e*v
                float s2 = __builtin_amdgcn_rcpf(1.0f + EXP2(-wv));
                float tv = fmaf(2.0f, s2, -1.0f);
                hn[rg] = fmaf(zz, ho - tv, tv);
            }
            u32x2 pk;
            pk[0] = pkbf(hn[0], hn[1]);
            pk[1] = pkbf(hn[2], hn[3]);
            *(u32x2*)&Ah[p ^ 1][ro + cg * 16 + q * 4] = pk;
            if (dofc) {
                // fc partial (fp32, raw): reduce over q, publish via ds atomic
                float pf = hn[0] * fw.x + hn[1] * fw.y + hn[2] * fw.z + hn[3] * fw.w;
                pf += __shfl_xor(pf, 16);
                pf += __shfl_xor(pf, 32);
                if (q == 0) atomicAdd(&xnraw[t & 1][row], pf);
            }
        }
        __syncthreads();

        if (t == TH - 1)
            load_w(WaF, fcow, fcob, false);
        p ^= 1;
    }

    // ---- tail: last prediction (xn of final fore step) ----
    if (tid < NN)
        pred[((long)bb * TF + (TF - 1)) * NN + tid] =
            xnraw[(TH + TF - 1) & 1][tid] + fcbO;
}

extern "C" void kernel_launch(void* const* d_in, const int* in_sizes, int n_in,
                              void* d_out, int out_size, void* d_ws, size_t ws_size,
                              hipStream_t stream) {
    const float* feature = (const float*)d_in[0];
    const float* pm25    = (const float*)d_in[1];
    const float* adj     = (const float*)d_in[2];
    const float* angles  = (const float*)d_in[3];
    const float* W_ih_h  = (const float*)d_in[4];
    const float* W_hh_h  = (const float*)d_in[5];
    const float* b_ih_h  = (const float*)d_in[6];
    const float* b_hh_h  = (const float*)d_in[7];
    const float* fch_w   = (const float*)d_in[8];
    const float* fch_b   = (const float*)d_in[9];
    const float* cw0     = (const float*)d_in[10];
    const float* cw1     = (const float*)d_in[11];
    const float* cbb     = (const float*)d_in[12];
    const float* W_ih    = (const float*)d_in[13];
    const float* W_hh    = (const float*)d_in[14];
    const float* b_ih    = (const float*)d_in[15];
    const float* b_hh    = (const float*)d_in[16];
    const float* fco_w   = (const float*)d_in[17];
    const float* fco_b   = (const float*)d_in[18];
    float* pred = (float*)d_out;

    char* ws = (char*)d_ws;
    size_t off = 0;
    unsigned short* WaH   = (unsigned short*)(ws + off); off += (size_t)NG2 * KA * 2;  //   204,800
    unsigned short* WaF   = (unsigned short*)(ws + off); off += (size_t)NG2 * KA * 2;
    float4*         edges = (float4*)(ws + off);         off += (size_t)NN * NN * 16;  //   541,696
    int*            cnt   = (int*)(ws + off);            off += 16;
    unsigned short* phist = (unsigned short*)(ws + off); off += (size_t)BB * TH * NN * 2; // 2,260,992
    char*           xrec  = (char*)(ws + off);
    off += (size_t)BB * TF * REC_F;                                                    // 54,263,808

    hipMemsetAsync(cnt, 0, 16, stream);
    prep_weights<<<(NG2 * KA + 255) / 256, 256, 0, stream>>>(
        W_hh_h, W_ih_h, W_hh, W_ih, b_ih_h, b_hh_h, b_ih, b_hh, fch_w, fch_b,
        WaH, WaF);
    prep_edges<<<(NN * NN + 255) / 256, 256, 0, stream>>>(angles, adj, edges, cnt);
    prep_hist<<<(BB * TH * NN + 255) / 256, 256, 0, stream>>>(pm25, phist);
    prep_graph<<<BB * TF, 1024, 0, stream>>>(
        feature, edges, cnt, cw0, cw1, cbb, xrec);

    fused_dgc<<<BB, NT, 0, stream>>>(
        WaH, WaF, fch_w, fch_b, fco_w, fco_b, cw0, cw1, xrec, phist, pred);
}